// Round 8
// baseline (1435.724 us; speedup 1.0000x reference)
//
#include <hip/hip_runtime.h>

// Levelized STA, R8: kernel-per-step chain with ATOMIC-FREE backward.
// R2-R7 post-mortems: ~16us/step floor invariant under traffic halving,
// persistent launch, 4x occupancy, padded atomic targets. Last untested
// suspect shared by all: 262K scatter-atomics/step. R8 removes them via a
// one-time CSR transpose of the fanin graph (prologue, fully parallel);
// backward becomes gather-min, bit-exact (fp32 min is order-independent).
//
// d_out (floats): [0,LP) arrival | [LP,2LP) required | [2LP,3LP) slack
//                 | [3LP..) mask as 0.0/1.0
// d_ws (ints): esrc | CSR entries | offs | counts | cursors(->ends) | rc | bits | partials
constexpr int L = 32;
constexpr int P = 131072;          // 2^17
constexpr int LP = L * P;
constexpr int LM1 = L - 1;
constexpr int APL = 2 * P;         // arcs per level = 262144 = 2^18
constexpr int NARC = LM1 * APL;    // 8,126,464
constexpr int NNETS = 1000000;
constexpr float TPER = 10.0f;
constexpr float NEGV = -1e30f;
constexpr int SRCMASK = P - 1;

// ws layout (int offsets)
constexpr size_t WS_ESRC = 0;                          // NARC
constexpr size_t WS_ENT  = WS_ESRC + (size_t)NARC;     // LM1*APL
constexpr size_t WS_OFF  = WS_ENT + (size_t)LM1 * APL; // LM1*P
constexpr size_t WS_CNT  = WS_OFF + (size_t)LM1 * P;   // LM1*P
constexpr size_t WS_CUR  = WS_CNT + (size_t)LM1 * P;   // LM1*P
constexpr size_t WS_RC   = WS_CUR + (size_t)LM1 * P;   // LP (floats)
constexpr size_t WS_BITS = WS_RC + (size_t)LP;         // 32768
constexpr size_t WS_PART = WS_BITS + 32768;            // LM1*128
constexpr size_t WS_END  = WS_PART + (size_t)LM1 * 128;

// Float atomic-min (fallback path only); exact for all sign mixes.
__device__ __forceinline__ void atomic_min_f32(float* addr, float val) {
  if (val >= 0.0f) {
    atomicMin(reinterpret_cast<int*>(addr), __float_as_int(val));
  } else {
    atomicMax(reinterpret_cast<unsigned int*>(addr), __float_as_uint(val));
  }
}

// ---- prologue kernels (all fully parallel; kernel boundaries = coherence) --

// init: arr[0]=delays[0]; req[L-1]=TPER; rc[L-1]=TPER-delays[L-1]; mask->float.
__global__ __launch_bounds__(256) void sta_init(
    const float* __restrict__ delays, const int* __restrict__ mask,
    float* __restrict__ out, int* __restrict__ ws) {
  const int p = blockIdx.x * blockDim.x + threadIdx.x;  // [0,P)
  float* rc = reinterpret_cast<float*>(ws + WS_RC);
  out[p] = delays[p];                                   // arr level 0
  const float dl = delays[(L - 1) * P + p];
  out[LP + (L - 1) * P + p] = TPER;                     // req level L-1
  rc[(L - 1) * P + p] = TPER - dl;
  float* mf = out + 3 * LP;
  const int base = p * 8;
  if (base + 7 < NNETS) {
    const int4 a = *reinterpret_cast<const int4*>(mask + base);
    const int4 b = *reinterpret_cast<const int4*>(mask + base + 4);
    float4 fa = {a.x ? 1.0f : 0.0f, a.y ? 1.0f : 0.0f, a.z ? 1.0f : 0.0f,
                 a.w ? 1.0f : 0.0f};
    float4 fb = {b.x ? 1.0f : 0.0f, b.y ? 1.0f : 0.0f, b.z ? 1.0f : 0.0f,
                 b.w ? 1.0f : 0.0f};
    *reinterpret_cast<float4*>(mf + base) = fa;
    *reinterpret_cast<float4*>(mf + base + 4) = fb;
  } else {
    for (int j = 0; j < 8; ++j)
      if (base + j < NNETS) mf[base + j] = mask[base + j] ? 1.0f : 0.0f;
  }
}

// bits: net-ignore bit-vector via wave ballot.
__global__ __launch_bounds__(256) void sta_bits(const int* __restrict__ mask,
                                                int* __restrict__ ws) {
  const int t = blockIdx.x * blockDim.x + threadIdx.x;  // [0,P)
  const int lane = threadIdx.x & 63;
  int* bits = ws + WS_BITS;
#pragma unroll
  for (int r = 0; r < 8; ++r) {
    const int idx = r * P + t;
    int mv = 0;
    if (idx < NNETS) mv = mask[idx];
    unsigned long long bal = __ballot(mv != 0);
    if (lane == 0)
      *reinterpret_cast<unsigned long long*>(
          ws + WS_BITS + ((r * P + (t & ~63)) >> 5)) = bal;
  }
  (void)bits;
}

// esrc = src | (ignored<<31); bit probes are L2-resident (125KB).
__global__ __launch_bounds__(256) void sta_esrc(const int* __restrict__ src,
                                                const int* __restrict__ net,
                                                int* __restrict__ ws) {
  const int a4 = (blockIdx.x * blockDim.x + threadIdx.x) * 4;
  const int* bits = ws + WS_BITS;
  if (a4 < NARC) {
    int4 s = *reinterpret_cast<const int4*>(src + a4);
    int4 n = *reinterpret_cast<const int4*>(net + a4);
    s.x |= ((bits[n.x >> 5] >> (n.x & 31)) & 1) << 31;
    s.y |= ((bits[n.y >> 5] >> (n.y & 31)) & 1) << 31;
    s.z |= ((bits[n.z >> 5] >> (n.z & 31)) & 1) << 31;
    s.w |= ((bits[n.w >> 5] >> (n.w & 31)) & 1) << 31;
    *reinterpret_cast<int4*>(ws + WS_ESRC + a4) = s;
  }
}

// count: fanout histogram per (level, source pin). Valid arcs only.
__global__ __launch_bounds__(256) void sta_count(int* __restrict__ ws) {
  const int g4 = (blockIdx.x * blockDim.x + threadIdx.x) * 4;
  int* cnt = ws + WS_CNT;
  if (g4 < NARC) {
    const int4 e = *reinterpret_cast<const int4*>(ws + WS_ESRC + g4);
#pragma unroll
    for (int k = 0; k < 4; ++k) {
      const int s = (&e.x)[k];
      if (s >= 0) {
        const int l = (g4 + k) >> 18;  // APL = 2^18
        atomicAdd(cnt + l * P + s, 1);
      }
    }
  }
}

// scan1: per-block (1024 counts) exclusive scan -> offs; block totals -> part.
__global__ __launch_bounds__(256) void sta_scan1(int* __restrict__ ws) {
  __shared__ int sd[256];
  const int l = blockIdx.x >> 7;        // 128 blocks per level
  const int blk = blockIdx.x & 127;
  const int t = threadIdx.x;
  const int base = l * P + blk * 1024;  // int index into counts/offs
  const int4 c = *reinterpret_cast<const int4*>(ws + WS_CNT + base + t * 4);
  const int s = c.x + c.y + c.z + c.w;
  sd[t] = s;
  __syncthreads();
  // Hillis-Steele inclusive scan over 256
  for (int off = 1; off < 256; off <<= 1) {
    int v = (t >= off) ? sd[t - off] : 0;
    __syncthreads();
    sd[t] += v;
    __syncthreads();
  }
  const int ex = sd[t] - s;  // exclusive
  int4 o;
  o.x = ex;
  o.y = ex + c.x;
  o.z = o.y + c.y;
  o.w = o.z + c.z;
  *reinterpret_cast<int4*>(ws + WS_OFF + base + t * 4) = o;
  if (t == 255) ws[WS_PART + l * 128 + blk] = sd[255];
}

// scan2: exclusive scan of the 128 block totals per level.
__global__ __launch_bounds__(128) void sta_scan2(int* __restrict__ ws) {
  __shared__ int sd[128];
  const int l = blockIdx.x;
  const int t = threadIdx.x;
  const int v = ws[WS_PART + l * 128 + t];
  sd[t] = v;
  __syncthreads();
  for (int off = 1; off < 128; off <<= 1) {
    int u = (t >= off) ? sd[t - off] : 0;
    __syncthreads();
    sd[t] += u;
    __syncthreads();
  }
  ws[WS_PART + l * 128 + t] = sd[t] - v;  // exclusive
}

// scan3: add block bases into offs; cursors = offs.
__global__ __launch_bounds__(256) void sta_scan3(int* __restrict__ ws) {
  const int l = blockIdx.x >> 7;
  const int blk = blockIdx.x & 127;
  const int t = threadIdx.x;
  const int base = l * P + blk * 1024;
  const int add = ws[WS_PART + l * 128 + blk];
  int4 o = *reinterpret_cast<const int4*>(ws + WS_OFF + base + t * 4);
  o.x += add; o.y += add; o.z += add; o.w += add;
  *reinterpret_cast<int4*>(ws + WS_OFF + base + t * 4) = o;
  *reinterpret_cast<int4*>(ws + WS_CUR + base + t * 4) = o;
}

// fill: place each valid arc's DEST pin into its source's CSR slot.
// After this, cur[l*P+s] == end index (offs + count).
__global__ __launch_bounds__(256) void sta_fill(int* __restrict__ ws) {
  const int g4 = (blockIdx.x * blockDim.x + threadIdx.x) * 4;
  int* cur = ws + WS_CUR;
  int* ent = ws + WS_ENT;
  if (g4 < NARC) {
    const int4 e = *reinterpret_cast<const int4*>(ws + WS_ESRC + g4);
#pragma unroll
    for (int k = 0; k < 4; ++k) {
      const int s = (&e.x)[k];
      if (s >= 0) {
        const int g = g4 + k;
        const int l = g >> 18;
        const int slot = atomicAdd(cur + l * P + s, 1);
        ent[(size_t)l * APL + slot] = (g & (APL - 1)) >> 1;  // dest pin
      }
    }
  }
}

// ---- fused step i: fwd gather-max (level lf=i) + bwd gather-min (lb=L-1-i).
// No atomics. rc[l] = req[l]-delays[l], written by the bwd that makes req[l].
__global__ __launch_bounds__(256) void sta_step(
    const float* __restrict__ delays, float* __restrict__ out,
    int* __restrict__ ws, int i) {
  const int p = blockIdx.x * blockDim.x + threadIdx.x;  // [0,P)
  float* arr = out;
  float* req = out + LP;
  float* rc = reinterpret_cast<float*>(ws + WS_RC);
  const int lf = i, lb = L - 1 - i;
  {  // forward
    const float d = delays[lf * P + p];
    const int2 s2 = *reinterpret_cast<const int2*>(ws + WS_ESRC +
                                                   (size_t)(lf - 1) * APL + p * 2);
    const float* ap = arr + (size_t)(lf - 1) * P;
    float v0 = ap[s2.x & SRCMASK] + d;
    float v1 = ap[s2.y & SRCMASK] + d;
    if (s2.x < 0) v0 = NEGV;
    if (s2.y < 0) v1 = NEGV;
    arr[(size_t)lf * P + p] = fmaxf(fmaxf(v0, v1), d);
  }
  {  // backward: gather-min over this pin's fanout arcs
    const int b = ws[WS_OFF + lb * P + p];
    const int e = ws[WS_CUR + lb * P + p];
    const int* ep = ws + WS_ENT + (size_t)lb * APL;
    const float* rcp = rc + (size_t)(lb + 1) * P;
    float m = TPER;
    for (int j = b; j < e; ++j) m = fminf(m, rcp[ep[j]]);
    req[(size_t)lb * P + p] = m;
    rc[(size_t)lb * P + p] = m - delays[lb * P + p];
  }
}

// Epilogue: slack = required - arrival.
__global__ __launch_bounds__(256) void sta_slack(float* __restrict__ out) {
  int i4 = (blockIdx.x * blockDim.x + threadIdx.x) * 4;
  if (i4 < LP) {
    float4 a = *reinterpret_cast<const float4*>(out + i4);
    float4 r = *reinterpret_cast<const float4*>(out + LP + i4);
    float4 s = {r.x - a.x, r.y - a.y, r.z - a.z, r.w - a.w};
    *reinterpret_cast<float4*>(out + 2 * LP + i4) = s;
  }
}

// ---- proven R2 fallback chain (only if ws too small) ----
__global__ __launch_bounds__(256) void sta_init_fb(
    const float* __restrict__ delays, const int* __restrict__ mask,
    float* __restrict__ out) {
  int i4 = (blockIdx.x * blockDim.x + threadIdx.x) * 4;
  if (i4 < LP) {
    float4 ten = {TPER, TPER, TPER, TPER};
    *reinterpret_cast<float4*>(out + LP + i4) = ten;
    if (i4 < P)
      *reinterpret_cast<float4*>(out + i4) =
          *reinterpret_cast<const float4*>(delays + i4);
  }
  if (i4 < NNETS) {
    int4 m = *reinterpret_cast<const int4*>(mask + i4);
    float4 f = {(float)(m.x != 0), (float)(m.y != 0), (float)(m.z != 0),
                (float)(m.w != 0)};
    *reinterpret_cast<float4*>(out + 3 * LP + i4) = f;
  }
}

__global__ __launch_bounds__(256) void sta_step_direct(
    const float* __restrict__ delays, const int* __restrict__ src,
    const int* __restrict__ net, const int* __restrict__ mask,
    float* __restrict__ out, int i) {
  const int p = blockIdx.x * blockDim.x + threadIdx.x;
  float* arr = out;
  float* req = out + LP;
  const int lf = i, lb = L - 1 - i;
  {
    const float d = delays[lf * P + p];
    const int2 s = *reinterpret_cast<const int2*>(src + (size_t)(lf - 1) * P * 2 + p * 2);
    const int2 n = *reinterpret_cast<const int2*>(net + (size_t)(lf - 1) * P * 2 + p * 2);
    const float* ap = arr + (lf - 1) * P;
    const float v0 = mask[n.x] ? NEGV : ap[s.x] + d;
    const float v1 = mask[n.y] ? NEGV : ap[s.y] + d;
    arr[lf * P + p] = fmaxf(fmaxf(v0, v1), d);
  }
  {
    const float c = req[(lb + 1) * P + p] - delays[(lb + 1) * P + p];
    const int2 s = *reinterpret_cast<const int2*>(src + (size_t)lb * P * 2 + p * 2);
    const int2 n = *reinterpret_cast<const int2*>(net + (size_t)lb * P * 2 + p * 2);
    float* rp = req + lb * P;
    if (!mask[n.x]) atomic_min_f32(rp + s.x, c);
    if (!mask[n.y]) atomic_min_f32(rp + s.y, c);
  }
}

extern "C" void kernel_launch(void* const* d_in, const int* in_sizes, int n_in,
                              void* d_out, int out_size, void* d_ws, size_t ws_size,
                              hipStream_t stream) {
  const float* delays = (const float*)d_in[0];
  const int* src = (const int*)d_in[1];
  const int* net = (const int*)d_in[2];
  const int* mask = (const int*)d_in[3];  // JAX bool delivered as int32
  float* out = (float*)d_out;
  int* ws = (int*)d_ws;

  if (ws_size >= WS_END * sizeof(int)) {
    sta_init<<<P / 256, 256, 0, stream>>>(delays, mask, out, ws);
    sta_bits<<<P / 256, 256, 0, stream>>>(mask, ws);
    sta_esrc<<<NARC / 4 / 256, 256, 0, stream>>>(src, net, ws);
    hipMemsetAsync((char*)d_ws + WS_CNT * sizeof(int), 0,
                   (size_t)LM1 * P * sizeof(int), stream);
    sta_count<<<NARC / 4 / 256, 256, 0, stream>>>(ws);
    sta_scan1<<<LM1 * 128, 256, 0, stream>>>(ws);
    sta_scan2<<<LM1, 128, 0, stream>>>(ws);
    sta_scan3<<<LM1 * 128, 256, 0, stream>>>(ws);
    sta_fill<<<NARC / 4 / 256, 256, 0, stream>>>(ws);
    for (int i = 1; i < L; ++i)
      sta_step<<<P / 256, 256, 0, stream>>>(delays, out, ws, i);
    sta_slack<<<LP / 1024, 256, 0, stream>>>(out);
    return;
  }
  // fallback (R2-proven)
  sta_init_fb<<<LP / 1024, 256, 0, stream>>>(delays, mask, out);
  for (int i = 1; i < L; ++i)
    sta_step_direct<<<P / 256, 256, 0, stream>>>(delays, src, net, mask, out, i);
  sta_slack<<<LP / 1024, 256, 0, stream>>>(out);
}

// Round 9
// 514.843 us; speedup vs baseline: 2.7887x; 2.7887x over previous
//
#include <hip/hip_runtime.h>

// Levelized STA, R9: atomic-free step chain via bucketed per-level CSR.
// Measured invariant R2-R8: scattered DEVICE-scope RMW ops run at ~16-22/ns
// aggregate (262K atomics/step = 14.5us floor); random READS run ~117/ns.
// So: backward scatter-min -> per-bucket gather + LDS-scope min. No device
// atomics anywhere on the 31-step chain.
//
// d_out (floats): [0,LP) arrival | [LP,2LP) required | [2LP,3LP) slack | mask01
// d_ws (ints): esrc | ent(packed bucket-CSR) | partials | cnt | off | cur | rc | bits
constexpr int L = 32;
constexpr int P = 131072;          // 2^17
constexpr int LP = L * P;
constexpr int LM1 = L - 1;
constexpr int APL = 2 * P;         // arcs per level = 262144
constexpr int NARC = LM1 * APL;    // 8,126,464
constexpr int NNETS = 1000000;
constexpr float TPER = 10.0f;
constexpr float NEGV = -1e30f;
constexpr int SRCMASK = P - 1;
constexpr int NBKT = 128;          // buckets per level (1024 pins each)
constexpr int BPIN = P / NBKT;     // 1024 pins per bucket
constexpr int CHBLK = 64;          // hist/fill blocks per level (4096 arcs each)
constexpr unsigned ENC_TPER = 0xC1200000u;  // enc(10.0f)

// ws layout (int offsets)
constexpr size_t WS_ESRC = 0;                              // NARC
constexpr size_t WS_ENT  = WS_ESRC + (size_t)NARC;         // LM1*APL
constexpr size_t WS_PART = WS_ENT + (size_t)LM1 * APL;     // LM1*CHBLK*NBKT
constexpr size_t WS_CNT  = WS_PART + (size_t)LM1 * CHBLK * NBKT;  // LM1*NBKT
constexpr size_t WS_OFF  = WS_CNT + (size_t)LM1 * NBKT;
constexpr size_t WS_CUR  = WS_OFF + (size_t)LM1 * NBKT;
constexpr size_t WS_RC   = WS_CUR + (size_t)LM1 * NBKT;    // LP floats
constexpr size_t WS_BITS = WS_RC + (size_t)LP;             // 32768
constexpr size_t WS_END  = WS_BITS + 32768;

// Monotone unsigned encoding of float: f1<f2 <=> enc(f1)<enc(f2) (unsigned).
__device__ __forceinline__ unsigned enc_f(float f) {
  int b = __float_as_int(f);
  return b >= 0 ? ((unsigned)b ^ 0x80000000u) : ~(unsigned)b;
}
__device__ __forceinline__ float dec_f(unsigned k) {
  int b = (k & 0x80000000u) ? (int)(k ^ 0x80000000u) : (int)~k;
  return __int_as_float(b);
}

// Device-scope float atomic-min (fallback path only).
__device__ __forceinline__ void atomic_min_f32(float* addr, float val) {
  if (val >= 0.0f) {
    atomicMin(reinterpret_cast<int*>(addr), __float_as_int(val));
  } else {
    atomicMax(reinterpret_cast<unsigned int*>(addr), __float_as_uint(val));
  }
}

// ---- prologue kernels (fully parallel; kernel boundaries = coherence) ----

// init: arr[0]=delays[0]; req[L-1]=TPER; rc[L-1]=TPER-delays[L-1]; mask->float.
__global__ __launch_bounds__(256) void sta_init(
    const float* __restrict__ delays, const int* __restrict__ mask,
    float* __restrict__ out, int* __restrict__ ws) {
  const int p = blockIdx.x * blockDim.x + threadIdx.x;  // [0,P)
  float* rc = reinterpret_cast<float*>(ws + WS_RC);
  out[p] = delays[p];
  out[LP + (L - 1) * P + p] = TPER;
  rc[(size_t)(L - 1) * P + p] = TPER - delays[(L - 1) * P + p];
  float* mf = out + 3 * LP;
  const int base = p * 8;
  if (base + 7 < NNETS) {
    const int4 a = *reinterpret_cast<const int4*>(mask + base);
    const int4 b = *reinterpret_cast<const int4*>(mask + base + 4);
    float4 fa = {a.x ? 1.0f : 0.0f, a.y ? 1.0f : 0.0f, a.z ? 1.0f : 0.0f,
                 a.w ? 1.0f : 0.0f};
    float4 fb = {b.x ? 1.0f : 0.0f, b.y ? 1.0f : 0.0f, b.z ? 1.0f : 0.0f,
                 b.w ? 1.0f : 0.0f};
    *reinterpret_cast<float4*>(mf + base) = fa;
    *reinterpret_cast<float4*>(mf + base + 4) = fb;
  } else {
    for (int j = 0; j < 8; ++j)
      if (base + j < NNETS) mf[base + j] = mask[base + j] ? 1.0f : 0.0f;
  }
}

// bits: net-ignore bit-vector via wave ballot.
__global__ __launch_bounds__(256) void sta_bits(const int* __restrict__ mask,
                                                int* __restrict__ ws) {
  const int t = blockIdx.x * blockDim.x + threadIdx.x;  // [0,P)
  const int lane = threadIdx.x & 63;
#pragma unroll
  for (int r = 0; r < 8; ++r) {
    const int idx = r * P + t;
    int mv = 0;
    if (idx < NNETS) mv = mask[idx];
    unsigned long long bal = __ballot(mv != 0);
    if (lane == 0)
      *reinterpret_cast<unsigned long long*>(
          ws + WS_BITS + ((r * P + (t & ~63)) >> 5)) = bal;
  }
}

// esrc = src | (ignored<<31); bit probes L2-resident (125KB).
__global__ __launch_bounds__(256) void sta_esrc(const int* __restrict__ src,
                                                const int* __restrict__ net,
                                                int* __restrict__ ws) {
  const int a4 = (blockIdx.x * blockDim.x + threadIdx.x) * 4;
  const int* bits = ws + WS_BITS;
  if (a4 < NARC) {
    int4 s = *reinterpret_cast<const int4*>(src + a4);
    int4 n = *reinterpret_cast<const int4*>(net + a4);
    s.x |= ((bits[n.x >> 5] >> (n.x & 31)) & 1) << 31;
    s.y |= ((bits[n.y >> 5] >> (n.y & 31)) & 1) << 31;
    s.z |= ((bits[n.z >> 5] >> (n.z & 31)) & 1) << 31;
    s.w |= ((bits[n.w >> 5] >> (n.w & 31)) & 1) << 31;
    *reinterpret_cast<int4*>(ws + WS_ESRC + a4) = s;
  }
}

// hist: per-(level-chunk) bucket histograms -> partials (plain coalesced writes).
__global__ __launch_bounds__(256) void sta_hist(int* __restrict__ ws) {
  __shared__ int h[NBKT];
  const int g = blockIdx.x;            // [0, LM1*CHBLK)
  const int l = g >> 6, chunk = g & 63;
  const int t = threadIdx.x;
  if (t < NBKT) h[t] = 0;
  __syncthreads();
  const size_t base = (size_t)l * APL + chunk * 4096;
#pragma unroll
  for (int r = 0; r < 4; ++r) {
    const int4 e = *reinterpret_cast<const int4*>(ws + WS_ESRC + base +
                                                  r * 1024 + t * 4);
#pragma unroll
    for (int k = 0; k < 4; ++k) {
      const int s = (&e.x)[k];
      if (s >= 0) atomicAdd(&h[s >> 10], 1);
    }
  }
  __syncthreads();
  if (t < NBKT) ws[WS_PART + (size_t)g * NBKT + t] = h[t];
}

// scan: cnt[l][b] = sum partials; per-level exclusive scan -> off, cur.
__global__ __launch_bounds__(NBKT) void sta_scan(int* __restrict__ ws) {
  __shared__ int sd[NBKT];
  const int l = blockIdx.x, t = threadIdx.x;
  int c = 0;
  for (int i = 0; i < CHBLK; ++i)
    c += ws[WS_PART + ((size_t)l * CHBLK + i) * NBKT + t];
  ws[WS_CNT + l * NBKT + t] = c;
  sd[t] = c;
  __syncthreads();
  for (int off = 1; off < NBKT; off <<= 1) {
    int v = (t >= off) ? sd[t - off] : 0;
    __syncthreads();
    sd[t] += v;
    __syncthreads();
  }
  const int ex = sd[t] - c;
  ws[WS_OFF + l * NBKT + t] = ex;
  ws[WS_CUR + l * NBKT + t] = ex;
}

// fill: bucket-CSR of packed words (dest<<10 | src_low). Reservation via
// 128 device atomicAdds per 4096-arc block (254K total, ~14us).
__global__ __launch_bounds__(256) void sta_fill(int* __restrict__ ws) {
  __shared__ int h[NBKT], base_s[NBKT];
  const int g = blockIdx.x;
  const int l = g >> 6, chunk = g & 63;
  const int t = threadIdx.x;
  if (t < NBKT) h[t] = 0;
  __syncthreads();
  const size_t base = (size_t)l * APL + chunk * 4096;
  int4 ev[4];
#pragma unroll
  for (int r = 0; r < 4; ++r) {
    ev[r] = *reinterpret_cast<const int4*>(ws + WS_ESRC + base + r * 1024 + t * 4);
#pragma unroll
    for (int k = 0; k < 4; ++k) {
      const int s = (&ev[r].x)[k];
      if (s >= 0) atomicAdd(&h[s >> 10], 1);
    }
  }
  __syncthreads();
  if (t < NBKT) {
    base_s[t] = atomicAdd(ws + WS_CUR + l * NBKT + t, h[t]);
    h[t] = 0;
  }
  __syncthreads();
  int* ent = ws + WS_ENT + (size_t)l * APL;
#pragma unroll
  for (int r = 0; r < 4; ++r) {
#pragma unroll
    for (int k = 0; k < 4; ++k) {
      const int s = (&ev[r].x)[k];
      if (s >= 0) {
        const int b = s >> 10;
        const int rank = atomicAdd(&h[b], 1);
        const int la = chunk * 4096 + r * 1024 + t * 4 + k;  // level-local arc
        ent[base_s[b] + rank] = ((la >> 1) << 10) | (s & 1023);
      }
    }
  }
}

// ---- fused step i: fwd gather-max (512 blocks) + bwd bucket-min (128 blocks).
// NO device atomics. rc[l] = req[l]-delays[l] written alongside req[l].
__global__ __launch_bounds__(256) void sta_step(
    const float* __restrict__ delays, float* __restrict__ out,
    int* __restrict__ ws, int i) {
  float* arr = out;
  float* req = out + LP;
  float* rc = reinterpret_cast<float*>(ws + WS_RC);
  if (blockIdx.x < 512) {  // forward level lf=i
    const int p = blockIdx.x * 256 + threadIdx.x;
    const int lf = i;
    const float d = delays[lf * P + p];
    const int2 s2 = *reinterpret_cast<const int2*>(ws + WS_ESRC +
                                                   (size_t)(lf - 1) * APL + p * 2);
    const float* ap = arr + (size_t)(lf - 1) * P;
    float v0 = ap[s2.x & SRCMASK] + d;
    float v1 = ap[s2.y & SRCMASK] + d;
    if (s2.x < 0) v0 = NEGV;
    if (s2.y < 0) v1 = NEGV;
    arr[(size_t)lf * P + p] = fmaxf(fmaxf(v0, v1), d);
  } else {                 // backward level lb=L-1-i, bucket b
    const int b = blockIdx.x - 512;
    const int lb = L - 1 - i;
    const int t = threadIdx.x;
    __shared__ unsigned rmin[BPIN];
    for (int j = t; j < BPIN; j += 256) rmin[j] = ENC_TPER;
    __syncthreads();
    const int off = ws[WS_OFF + lb * NBKT + b];
    const int cnt = ws[WS_CNT + lb * NBKT + b];
    const int* ep = ws + WS_ENT + (size_t)lb * APL + off;
    const float* rcp = rc + (size_t)(lb + 1) * P;
    for (int j = t; j < cnt; j += 256) {
      const int w = ep[j];
      const float c = rcp[w >> 10];            // random READ (fast path)
      atomicMin(&rmin[w & 1023], enc_f(c));    // LDS-scope min
    }
    __syncthreads();
    for (int j = t; j < BPIN; j += 256) {
      const float rv = dec_f(rmin[j]);
      const int pin = b * BPIN + j;
      req[(size_t)lb * P + pin] = rv;
      rc[(size_t)lb * P + pin] = rv - delays[lb * P + pin];
    }
  }
}

// Epilogue: slack = required - arrival.
__global__ __launch_bounds__(256) void sta_slack(float* __restrict__ out) {
  int i4 = (blockIdx.x * blockDim.x + threadIdx.x) * 4;
  if (i4 < LP) {
    float4 a = *reinterpret_cast<const float4*>(out + i4);
    float4 r = *reinterpret_cast<const float4*>(out + LP + i4);
    float4 s = {r.x - a.x, r.y - a.y, r.z - a.z, r.w - a.w};
    *reinterpret_cast<float4*>(out + 2 * LP + i4) = s;
  }
}

// ---- proven R2 fallback chain (only if ws too small) ----
__global__ __launch_bounds__(256) void sta_init_fb(
    const float* __restrict__ delays, const int* __restrict__ mask,
    float* __restrict__ out) {
  int i4 = (blockIdx.x * blockDim.x + threadIdx.x) * 4;
  if (i4 < LP) {
    float4 ten = {TPER, TPER, TPER, TPER};
    *reinterpret_cast<float4*>(out + LP + i4) = ten;
    if (i4 < P)
      *reinterpret_cast<float4*>(out + i4) =
          *reinterpret_cast<const float4*>(delays + i4);
  }
  if (i4 < NNETS) {
    int4 m = *reinterpret_cast<const int4*>(mask + i4);
    float4 f = {(float)(m.x != 0), (float)(m.y != 0), (float)(m.z != 0),
                (float)(m.w != 0)};
    *reinterpret_cast<float4*>(out + 3 * LP + i4) = f;
  }
}

__global__ __launch_bounds__(256) void sta_step_direct(
    const float* __restrict__ delays, const int* __restrict__ src,
    const int* __restrict__ net, const int* __restrict__ mask,
    float* __restrict__ out, int i) {
  const int p = blockIdx.x * blockDim.x + threadIdx.x;
  float* arr = out;
  float* req = out + LP;
  const int lf = i, lb = L - 1 - i;
  {
    const float d = delays[lf * P + p];
    const int2 s = *reinterpret_cast<const int2*>(src + (size_t)(lf - 1) * P * 2 + p * 2);
    const int2 n = *reinterpret_cast<const int2*>(net + (size_t)(lf - 1) * P * 2 + p * 2);
    const float* ap = arr + (lf - 1) * P;
    const float v0 = mask[n.x] ? NEGV : ap[s.x] + d;
    const float v1 = mask[n.y] ? NEGV : ap[s.y] + d;
    arr[lf * P + p] = fmaxf(fmaxf(v0, v1), d);
  }
  {
    const float c = req[(lb + 1) * P + p] - delays[(lb + 1) * P + p];
    const int2 s = *reinterpret_cast<const int2*>(src + (size_t)lb * P * 2 + p * 2);
    const int2 n = *reinterpret_cast<const int2*>(net + (size_t)lb * P * 2 + p * 2);
    float* rp = req + lb * P;
    if (!mask[n.x]) atomic_min_f32(rp + s.x, c);
    if (!mask[n.y]) atomic_min_f32(rp + s.y, c);
  }
}

extern "C" void kernel_launch(void* const* d_in, const int* in_sizes, int n_in,
                              void* d_out, int out_size, void* d_ws, size_t ws_size,
                              hipStream_t stream) {
  const float* delays = (const float*)d_in[0];
  const int* src = (const int*)d_in[1];
  const int* net = (const int*)d_in[2];
  const int* mask = (const int*)d_in[3];  // JAX bool delivered as int32
  float* out = (float*)d_out;
  int* ws = (int*)d_ws;

  if (ws_size >= WS_END * sizeof(int)) {
    sta_init<<<P / 256, 256, 0, stream>>>(delays, mask, out, ws);
    sta_bits<<<P / 256, 256, 0, stream>>>(mask, ws);
    sta_esrc<<<NARC / 4 / 256, 256, 0, stream>>>(src, net, ws);
    sta_hist<<<LM1 * CHBLK, 256, 0, stream>>>(ws);
    sta_scan<<<LM1, NBKT, 0, stream>>>(ws);
    sta_fill<<<LM1 * CHBLK, 256, 0, stream>>>(ws);
    for (int i = 1; i < L; ++i)
      sta_step<<<512 + NBKT, 256, 0, stream>>>(delays, out, ws, i);
    sta_slack<<<LP / 1024, 256, 0, stream>>>(out);
    return;
  }
  // fallback (R2-proven)
  sta_init_fb<<<LP / 1024, 256, 0, stream>>>(delays, mask, out);
  for (int i = 1; i < L; ++i)
    sta_step_direct<<<P / 256, 256, 0, stream>>>(delays, src, net, mask, out, i);
  sta_slack<<<LP / 1024, 256, 0, stream>>>(out);
}